// Round 1
// baseline (94.952 us; speedup 1.0000x reference)
//
#include <hip/hip_runtime.h>

// Shapes fixed by the reference:
//   x_LL : (8, 32, 128, 128)      f32
//   x    : (8, 4, 32, 128, 128)   f32  (channel 0 unused)
//   y    : (8, 32, 256, 256)      f32
//   out  : (8, 160, 256, 256)     f32  = cat(LL, LH, HL, HH, y) on axis 1
//
// out[b, c, 2i+p, 2j+q] = src[b, d, i, j] * K[p][q]  for c < 128 (d = c&31)
// out[b, 128+d, h, w]   = y[b, d, h, w]
//
// Haar rows (k[p][0], k[p][1]):
//   LL: p0 ( .5, .5)  p1 ( .5, .5)
//   LH: p0 (-.5, .5)  p1 (-.5, .5)
//   HL: p0 (-.5,-.5)  p1 ( .5, .5)
//   HH: p0 ( .5,-.5)  p1 (-.5, .5)

#define BB 8
#define DD 32
#define HH_IN 128
#define WW_IN 128
#define H2 256
#define W2 256
#define C_OUT 160            // 5 * DD
#define W4 64                // W2 / 4 float4 per output row

__global__ __launch_bounds__(256) void haar_iwt_cat_kernel(
    const float* __restrict__ xLL,
    const float* __restrict__ x,
    const float* __restrict__ y,
    float*       __restrict__ out,
    long long total4)
{
    const long long stride = (long long)gridDim.x * blockDim.x;
    for (long long idx = (long long)blockIdx.x * blockDim.x + threadIdx.x;
         idx < total4; idx += stride) {
        // idx = ((b*C_OUT + c)*H2 + h2)*W4 + w4
        const int w4       = (int)(idx & (W4 - 1));
        const long long t1 = idx >> 6;              // (b*C_OUT + c)*H2 + h2
        const int h2       = (int)(t1 & (H2 - 1));
        const long long bc = t1 >> 8;               // b*C_OUT + c
        const int c        = (int)(bc % C_OUT);
        const int b        = (int)(bc / C_OUT);

        float4 o;
        if (c >= 128) {
            // straight copy from y
            const int d = c - 128;
            const float4* src = (const float4*)(
                y + ((((long long)b * DD + d) * H2 + h2) * (long long)W2));
            o = src[w4];
        } else {
            const int sel = c >> 5;     // 0=LL 1=LH 2=HL 3=HH
            const int d   = c & 31;
            const int h   = h2 >> 1;
            const int p   = h2 & 1;
            const float* src;
            if (sel == 0) {
                src = xLL + ((((long long)b * DD + d) * HH_IN + h) * (long long)WW_IN);
            } else {
                src = x + (((((long long)b * 4 + sel) * DD + d) * HH_IN + h) * (long long)WW_IN);
            }
            const float2 v = ((const float2*)src)[w4];  // inputs j = 2*w4, 2*w4+1
            float k0, k1;
            switch (sel) {
                case 0:  k0 =  0.5f;              k1 =  0.5f; break;   // LL
                case 1:  k0 = -0.5f;              k1 =  0.5f; break;   // LH
                case 2:  k0 = p ?  0.5f : -0.5f;  k1 =  k0;   break;   // HL
                default: k0 = p ? -0.5f :  0.5f;  k1 = -k0;   break;   // HH
            }
            o.x = v.x * k0;
            o.y = v.x * k1;
            o.z = v.y * k0;
            o.w = v.y * k1;
        }
        ((float4*)out)[idx] = o;
    }
}

extern "C" void kernel_launch(void* const* d_in, const int* in_sizes, int n_in,
                              void* d_out, int out_size, void* d_ws, size_t ws_size,
                              hipStream_t stream) {
    const float* xLL = (const float*)d_in[0];
    const float* x   = (const float*)d_in[1];
    const float* y   = (const float*)d_in[2];
    float*       out = (float*)d_out;

    const long long total4 = (long long)BB * C_OUT * H2 * W4;  // 20,971,520
    const int block = 256;
    const int grid  = 2048;   // 256 CU x 8 blocks/CU; grid-stride covers the rest

    haar_iwt_cat_kernel<<<grid, block, 0, stream>>>(xLL, x, y, out, total4);
}

// Round 3
// 85.954 us; speedup vs baseline: 1.1047x; 1.1047x over previous
//
#include <hip/hip_runtime.h>

// Shapes fixed by the reference:
//   x_LL : (8, 32, 128, 128)      f32
//   x    : (8, 4, 32, 128, 128)   f32  (channel 0 unused)
//   y    : (8, 32, 256, 256)      f32
//   out  : (8, 160, 256, 256)     f32  = cat(LL, LH, HL, HH, y) on axis 1
//
// out[b, sel*32+d, 2i+p, 2j+q] = src[b, d, i, j] * K[sel][p][q]   (sel<4)
// out[b, 128+d,    h,    w   ] = y[b, d, h, w]                    (sel==4)
//
// One wave handles one (b, sel, d, i) unit = output rows 2i and 2i+1
// (or the y-copy row pair). lane j covers output cols 4j..4j+3:
//   - upsample: read float2 src[i][2j..2j+1] once, produce both rows
//     from registers (no cache-dependent re-read),
//   - stores: 2x global_store_dwordx4 nt, each 1 KiB/wave fully coalesced.

#define DD 32
#define H_IN 128
#define W_IN 128
#define H2 256
#define W2 256

// Native clang vector types — required by __builtin_nontemporal_*.
typedef float f32x4 __attribute__((ext_vector_type(4)));
typedef float f32x2 __attribute__((ext_vector_type(2)));

__global__ __launch_bounds__(256) void haar_iwt_cat_kernel(
    const float* __restrict__ xLL,
    const float* __restrict__ x,
    const float* __restrict__ y,
    float*       __restrict__ out)
{
    const unsigned tid  = threadIdx.x;
    const unsigned lane = tid & 63u;
    // wave-unit u = ((b*5 + sel)*32 + d)*128 + i   — all wave-uniform
    const unsigned u = blockIdx.x * 4u + (tid >> 6);

    const unsigned i = u & (H_IN - 1u);
    unsigned t = u >> 7;                 // (b*5 + sel)*32 + d
    const unsigned d = t & (DD - 1u);
    t >>= 5;                             // b*5 + sel, < 40
    const unsigned b   = t / 5u;         // 32-bit magic mul
    const unsigned sel = t - b * 5u;

    // out rows 2i, 2i+1 of channel c = sel*32 + d
    float* orow = out + (((size_t)(b * 160u + sel * 32u + d) * H2 + 2u * i) * W2);
    f32x4* o0 = ((f32x4*)orow) + lane;
    f32x4* o1 = ((f32x4*)(orow + W2)) + lane;

    if (sel == 4u) {
        const float* yrow = y + (((size_t)(b * DD + d) * H2 + 2u * i) * W2);
        const f32x4 v0 = __builtin_nontemporal_load(((const f32x4*)yrow) + lane);
        const f32x4 v1 = __builtin_nontemporal_load(((const f32x4*)(yrow + W2)) + lane);
        __builtin_nontemporal_store(v0, o0);
        __builtin_nontemporal_store(v1, o1);
        return;
    }

    const float* src = (sel == 0u)
        ? xLL + ((size_t)(b * DD + d) * H_IN + i) * W_IN
        : x   + ((size_t)((b * 4u + sel) * DD + d) * H_IN + i) * W_IN;
    const f32x2 v = __builtin_nontemporal_load(((const f32x2*)src) + lane);

    // K[sel] rows: (k00,k01) for p=0, (k10,k11) for p=1
    float k00, k01, k10, k11;
    switch (sel) {
        case 0u: k00 =  0.5f; k01 =  0.5f; k10 =  0.5f; k11 =  0.5f; break; // LL
        case 1u: k00 = -0.5f; k01 =  0.5f; k10 = -0.5f; k11 =  0.5f; break; // LH
        case 2u: k00 = -0.5f; k01 = -0.5f; k10 =  0.5f; k11 =  0.5f; break; // HL
        default: k00 =  0.5f; k01 = -0.5f; k10 = -0.5f; k11 =  0.5f; break; // HH
    }

    f32x4 r0, r1;
    r0.x = v.x * k00; r0.y = v.x * k01; r0.z = v.y * k00; r0.w = v.y * k01;
    r1.x = v.x * k10; r1.y = v.x * k11; r1.z = v.y * k10; r1.w = v.y * k11;
    __builtin_nontemporal_store(r0, o0);
    __builtin_nontemporal_store(r1, o1);
}

extern "C" void kernel_launch(void* const* d_in, const int* in_sizes, int n_in,
                              void* d_out, int out_size, void* d_ws, size_t ws_size,
                              hipStream_t stream) {
    const float* xLL = (const float*)d_in[0];
    const float* x   = (const float*)d_in[1];
    const float* y   = (const float*)d_in[2];
    float*       out = (float*)d_out;

    // wave-units: 8 b * 5 sel * 32 d * 128 i = 163,840; 4 waves per block
    const int grid  = 163840 / 4;   // 40,960 blocks
    const int block = 256;
    haar_iwt_cat_kernel<<<grid, block, 0, stream>>>(xLL, x, y, out);
}